// Round 10
// baseline (1679.597 us; speedup 1.0000x reference)
//
#include <hip/hip_runtime.h>

// Tree-GRU encoder, round 10: R9 skeleton (fused DT+TD, per-level dataflow
// flags, rotated chunk order, LDS hprev) with LDS-traffic-optimized geometry:
//  - 32 rows per wave (2 A-frags share each B read): 10 ds_reads per 24 MFMA
//    (was 16 per 12) -> LDS-port time per row ~0.62x.
//  - block tile 256 rows x 16 cols -> sequential tile rounds per block halve.
//  - LDS 160KB: B weights resident 96K | Xb 32K | Hb 32K.
//
// ws (~141 MB): wt 4x[1536][512] | Xc[NG][512] | Hdt|Htd|Hfd [NG][512] |
//               zrow[512] | ctr u32[520] | sched/meta/gidx/pslot

#define NL 256
#define NB 128
#define NH 512
#define NG (NB * NL)

typedef short short8 __attribute__((ext_vector_type(8)));
typedef float f32x4 __attribute__((ext_vector_type(4)));

__device__ __forceinline__ float bf2f(unsigned short u) {
  union { unsigned int i; float f; } c; c.i = ((unsigned int)u) << 16; return c.f;
}
__device__ __forceinline__ unsigned short f2bf(float f) {
  union { float f; unsigned int i; } c; c.f = f;
  return (unsigned short)((c.i + 0x7FFFu + ((c.i >> 16) & 1u)) >> 16);  // RNE
}
__device__ __forceinline__ short8 pk_bf16(f32x4 a, f32x4 b) {
  union { unsigned int u[4]; short8 s; } r;
  asm("v_cvt_pk_bf16_f32 %0, %1, %2" : "=v"(r.u[0]) : "v"(a[0]), "v"(a[1]));
  asm("v_cvt_pk_bf16_f32 %0, %1, %2" : "=v"(r.u[1]) : "v"(a[2]), "v"(a[3]));
  asm("v_cvt_pk_bf16_f32 %0, %1, %2" : "=v"(r.u[2]) : "v"(b[0]), "v"(b[1]));
  asm("v_cvt_pk_bf16_f32 %0, %1, %2" : "=v"(r.u[3]) : "v"(b[2]), "v"(b[3]));
  return r.s;
}
__device__ __forceinline__ void atom_pk_bf16(unsigned short* p, unsigned int ud) {
  asm volatile("global_atomic_pk_add_bf16 %0, %1, off" :: "v"((void*)p), "v"(ud) : "memory");
}

__device__ __forceinline__ void level_wait(unsigned int* c, unsigned int target) {
  if (threadIdx.x == 0) {
    while (__hip_atomic_load(c, __ATOMIC_RELAXED, __HIP_MEMORY_SCOPE_AGENT) < target)
      __builtin_amdgcn_s_sleep(2);
  }
  __syncthreads();
  __builtin_amdgcn_fence(__ATOMIC_ACQUIRE, "agent");
}

// ---- prep: 4 weight matrices [512][1536] f32 -> transposed [1536][512] bf16 ----
__global__ void prep_wt4(const float* __restrict__ w0, const float* __restrict__ w1,
                         const float* __restrict__ w2, const float* __restrict__ w3,
                         unsigned short* __restrict__ wt) {
  __shared__ float t[32][33];
  const float* w = blockIdx.z == 0 ? w0 : blockIdx.z == 1 ? w1 : blockIdx.z == 2 ? w2 : w3;
  unsigned short* dst = wt + (size_t)blockIdx.z * 1536 * 512;
  int n0 = blockIdx.x * 32, k0 = blockIdx.y * 32;
  int tx = threadIdx.x & 31, ty = threadIdx.x >> 5;
  #pragma unroll
  for (int i = 0; i < 4; ++i)
    t[ty + 8 * i][tx] = w[(size_t)(k0 + ty + 8 * i) * 1536 + n0 + tx];
  __syncthreads();
  #pragma unroll
  for (int i = 0; i < 4; ++i)
    dst[(size_t)(n0 + ty + 8 * i) * 512 + k0 + tx] = f2bf(t[tx][ty + 8 * i]);
}

// ---- prep: depths, level buckets, slots, parent slots (1 block, 256 thr) ----
__global__ void prep_sched(const int* __restrict__ td_pidx,
                           const float* __restrict__ td_pval,
                           int* __restrict__ sched, int* __restrict__ meta,
                           int* __restrict__ gidx, int* __restrict__ pslot) {
  __shared__ unsigned char dep[NB][NL];
  __shared__ unsigned short cnb[NB][256];
  __shared__ int cnt[256];
  __shared__ int off[257];
  __shared__ int dmax_s;
  const int tid = threadIdx.x;
  for (int j = tid; j < NB * 256; j += 256) ((unsigned short*)cnb)[j] = 0;
  if (tid == 0) dmax_s = 0;
  __syncthreads();
  if (tid < NB) {
    int b = tid, lmax = 0;
    for (int i = 0; i < NL; ++i) {
      float pv = td_pval[i * NB + b];
      int pi = td_pidx[i * NB + b];
      int d = (pv != 0.f) ? (int)dep[b][pi] + 1 : 0;   // head[i] < i
      dep[b][i] = (unsigned char)d;
      cnb[b][d]++;
      lmax = max(lmax, d);
    }
    atomicMax(&dmax_s, lmax);
  }
  __syncthreads();
  {
    int s = 0;
    for (int b = 0; b < NB; ++b) s += cnb[b][tid];
    cnt[tid] = s;
  }
  __syncthreads();
  if (tid == 0) {
    int s = 0;
    for (int d = 0; d < 256; ++d) { off[d] = s; s += cnt[d]; }
    off[256] = s;
  }
  __syncthreads();
  {
    int run = off[tid];
    for (int b = 0; b < NB; ++b) {
      int t = cnb[b][tid];
      cnb[b][tid] = (unsigned short)run;
      run += t;
    }
  }
  __syncthreads();
  if (tid < NB) {
    int b = tid;
    for (int i = 0; i < NL; ++i) {
      float pv = td_pval[i * NB + b];
      int pi = td_pidx[i * NB + b];
      int d = dep[b][i];
      int g = cnb[b][d]++;
      sched[g] = (b << 8) | i;
      gidx[b * NL + i] = g;
      pslot[g] = (pv != 0.f) ? gidx[b * NL + pi] : -1;
    }
  }
  if (tid == 0) meta[0] = dmax_s;
  __syncthreads();
  meta[1 + tid] = off[tid];
  meta[257 + tid] = cnt[tid];
}

// ---- prep: gather emb rows into slot order, f32 -> bf16 ----
__global__ void prep_xc(const float* __restrict__ emb, const int* __restrict__ sched,
                        unsigned short* __restrict__ Xc) {
  int g = blockIdx.x * 4 + (threadIdx.x >> 6);
  int lane = threadIdx.x & 63;
  int e = sched[g];
  int b = e >> 8, node = e & 255;
  const float* src = emb + ((size_t)node * NB + b) * 512 + lane * 8;
  f32x4 v0 = *(const f32x4*)src;
  f32x4 v1 = *(const f32x4*)(src + 4);
  *(short8*)(Xc + (size_t)g * 512 + lane * 8) = pk_bf16(v0, v1);
}

// ---- main fused kernel, flag-synced ----
// grid = 256 x 512 thr (8 waves, 1/CU). bi = cg*8 + pass*4 + rep.
// Block tile: 256 rows x 16 cols. Wave w owns rows [w*32, +32) (2 A-frags).
// LDS: B weights 98304 | Xb 32768 | Hb 32768 = 163840.
__launch_bounds__(512, 2)
__global__ void tree_gru(const float* __restrict__ dt_b,
                         const float* __restrict__ td_b,
                         const unsigned short* __restrict__ wt,
                         const unsigned short* __restrict__ Xc,
                         unsigned short* __restrict__ Hdt,
                         unsigned short* __restrict__ Htd,
                         unsigned short* __restrict__ Hfd,
                         const unsigned short* __restrict__ zrow,
                         const int* __restrict__ meta,
                         const int* __restrict__ pslot,
                         unsigned int* __restrict__ ctr,
                         const int* __restrict__ sched,
                         const int* __restrict__ root_index,
                         float* __restrict__ out) {
  extern __shared__ unsigned char lds[];
  const int tid = threadIdx.x;
  const int bi  = blockIdx.x;
  const int cg   = bi >> 3;          // 0..31 col group (16 cols)
  const int pass = (bi >> 2) & 1;    // 0 = DT bottom-up, 1 = TD top-down
  const int rep  = bi & 3;           // row-tile replica
  const int w  = tid >> 6, l = tid & 63;
  const int lm = l & 15, kg = l >> 4;
  const int col = cg * 16 + lm;

  // stage weight slices: [mat(Wx,Uh)][gate(r,z,n)][n16][k512] bf16, XOR-swizzled
  for (int idx = tid; idx < 6144; idx += 512) {
    int k8  = idx & 63;
    int n   = (idx >> 6) & 15;
    int g   = (idx >> 10) % 3;
    int mat = idx / 3072;
    const unsigned short* src = wt + (size_t)(pass * 2 + mat) * (1536 * 512)
                                   + (size_t)(g * 512 + cg * 16 + n) * 512 + k8 * 8;
    short8 v = *(const short8*)src;
    int off = ((mat * 3 + g) * 16 + n) * 1024 + ((k8 * 16) ^ ((n & 7) << 4));
    *(short8*)(lds + off) = v;
  }
  unsigned char* Xb = lds + 98304;
  unsigned char* Hb = lds + 98304 + 32768;
  __syncthreads();

  const float* bias = pass ? td_b : dt_b;
  const float br = bias[col], bz = bias[NH + col], bn = bias[2 * NH + col];
  const int base_wr = (0 * 16 + lm) * 1024;
  const int base_wz = (1 * 16 + lm) * 1024;
  const int base_wn = (2 * 16 + lm) * 1024;
  const int base_ur = (3 * 16 + lm) * 1024;
  const int base_uz = (4 * 16 + lm) * 1024;
  const int base_un = (5 * 16 + lm) * 1024;
  const int wswz = (lm & 7) << 4;
  const int srow = tid >> 1;                     // A-stage: 256 rows x 2 halves
  const int shalf = (tid & 1) * 4;               // 4 slot offset (64B)
  const int ck = cg >> 2;                        // chunk holding this block's cols
  const int ccw = 2 * ((cg & 3) * 16 + lm);      // byte off of col within chunk row
  const int ccslot = ccw >> 4, ccin = ccw & 15;
  const int Dmax = meta[0];
  unsigned int* doneP = ctr + pass * 256;

  for (int p = 0; p <= Dmax; ++p) {
    const int d = pass ? p : (Dmax - p);
    const int off_d = meta[1 + d];
    const int cnt_d = meta[257 + d];
    const int T = (cnt_d + 255) >> 8;
    if (T <= rep) continue;                      // no tiles -> no wait
    const int dl = pass ? d - 1 : d + 1;         // dependency level
    if (dl >= 0 && dl <= Dmax)
      level_wait(doneP + dl, (unsigned int)meta[257 + dl] * 32u);
    for (int t = rep; t < T; t += 4) {
      const int g0 = off_d + t * 256;
      const int rows = min(256, cnt_d - t * 256);
      // staging sources: row srow (clamped), 64B half each — coalesced
      const int gg = g0 + min(srow, rows - 1);
      const unsigned short* sx = Xc + (size_t)gg * 512 + (tid & 1) * 32;
      const unsigned short* sh;
      if (pass == 0) {
        sh = Hdt + (size_t)gg * 512 + (tid & 1) * 32;
      } else {
        int ps = pslot[gg];
        sh = (ps >= 0 ? Htd + (size_t)ps * 512 : zrow) + (tid & 1) * 32;
      }
      const int c0 = (ck + 1) & 7;               // rotated order ends at ck
      short8 rx[4], rh[4];
      #pragma unroll
      for (int j = 0; j < 4; ++j) {
        rx[j] = *(const short8*)(sx + c0 * 64 + j * 8);
        rh[j] = *(const short8*)(sh + c0 * 64 + j * 8);
      }
      f32x4 aR[2], aZ[2], aXN[2], aHN[2];
      #pragma unroll
      for (int f = 0; f < 2; ++f) {
        aR[f] = (f32x4){0,0,0,0}; aZ[f] = (f32x4){0,0,0,0};
        aXN[f] = (f32x4){0,0,0,0}; aHN[f] = (f32x4){0,0,0,0};
      }
      #pragma unroll
      for (int ci = 0; ci < 8; ++ci) {
        const int c = (ck + 1 + ci) & 7;
        __syncthreads();                         // prev chunk consumed
        #pragma unroll
        for (int j = 0; j < 4; ++j) {
          const int so = ((shalf + j) ^ (srow & 7)) << 4;
          *(short8*)(Xb + srow * 128 + so) = rx[j];
          *(short8*)(Hb + srow * 128 + so) = rh[j];
        }
        if (ci < 7) {
          const int cn = (ck + 2 + ci) & 7;
          #pragma unroll
          for (int j = 0; j < 4; ++j) {
            rx[j] = *(const short8*)(sx + cn * 64 + j * 8);
            rh[j] = *(const short8*)(sh + cn * 64 + j * 8);
          }
        }
        __syncthreads();                         // chunk visible
        #pragma unroll
        for (int ks = 0; ks < 2; ++ks) {
          const int so = (((ks << 2) | kg) ^ (lm & 7)) << 4;
          const int r0 = (w * 32 + lm) * 128;
          const int r1 = (w * 32 + 16 + lm) * 128;
          short8 ax0 = *(const short8*)(Xb + r0 + so);
          short8 ax1 = *(const short8*)(Xb + r1 + so);
          short8 ah0 = *(const short8*)(Hb + r0 + so);
          short8 ah1 = *(const short8*)(Hb + r1 + so);
          const int kb = (c * 128 + ks * 64 + kg * 16) ^ wswz;
          short8 bwr = *(const short8*)(lds + base_wr + kb);
          short8 bwz = *(const short8*)(lds + base_wz + kb);
          short8 bwn = *(const short8*)(lds + base_wn + kb);
          short8 bur = *(const short8*)(lds + base_ur + kb);
          short8 buz = *(const short8*)(lds + base_uz + kb);
          short8 bun = *(const short8*)(lds + base_un + kb);
          aR[0]  = __builtin_amdgcn_mfma_f32_16x16x32_bf16(ax0, bwr, aR[0], 0, 0, 0);
          aR[1]  = __builtin_amdgcn_mfma_f32_16x16x32_bf16(ax1, bwr, aR[1], 0, 0, 0);
          aZ[0]  = __builtin_amdgcn_mfma_f32_16x16x32_bf16(ax0, bwz, aZ[0], 0, 0, 0);
          aZ[1]  = __builtin_amdgcn_mfma_f32_16x16x32_bf16(ax1, bwz, aZ[1], 0, 0, 0);
          aXN[0] = __builtin_amdgcn_mfma_f32_16x16x32_bf16(ax0, bwn, aXN[0], 0, 0, 0);
          aXN[1] = __builtin_amdgcn_mfma_f32_16x16x32_bf16(ax1, bwn, aXN[1], 0, 0, 0);
          aR[0]  = __builtin_amdgcn_mfma_f32_16x16x32_bf16(ah0, bur, aR[0], 0, 0, 0);
          aR[1]  = __builtin_amdgcn_mfma_f32_16x16x32_bf16(ah1, bur, aR[1], 0, 0, 0);
          aZ[0]  = __builtin_amdgcn_mfma_f32_16x16x32_bf16(ah0, buz, aZ[0], 0, 0, 0);
          aZ[1]  = __builtin_amdgcn_mfma_f32_16x16x32_bf16(ah1, buz, aZ[1], 0, 0, 0);
          aHN[0] = __builtin_amdgcn_mfma_f32_16x16x32_bf16(ah0, bun, aHN[0], 0, 0, 0);
          aHN[1] = __builtin_amdgcn_mfma_f32_16x16x32_bf16(ah1, bun, aHN[1], 0, 0, 0);
        }
      }
      // epilogue: Hb holds chunk ck -> hprev from LDS. Row = w*32+f*16+kg*4+q.
      #pragma unroll
      for (int fq = 0; fq < 8; ++fq) {
        const int f = fq >> 2, q = fq & 3;
        const int r = w * 32 + f * 16 + kg * 4 + q;
        if (r >= rows) continue;
        const int g = g0 + r;
        const float hprev = bf2f(*(const unsigned short*)(
            Hb + r * 128 + (((ccslot ^ (r & 7)) << 4) | ccin)));
        float rr = 1.f / (1.f + __expf(-(aR[f][q] + br)));
        float zz = 1.f / (1.f + __expf(-(aZ[f][q] + bz)));
        float e2 = __expf(2.f * (aXN[f][q] + bn + rr * aHN[f][q]));
        float nn = (e2 - 1.f) / (e2 + 1.f);      // tanh
        float h = (1.f - zz) * nn + zz * hprev;
        float ho = __shfl_xor(h, 1);
        if (!(lm & 1)) {
          unsigned int ud;
          asm("v_cvt_pk_bf16_f32 %0, %1, %2" : "=v"(ud) : "v"(h), "v"(ho));
          if (pass == 0) {
            atom_pk_bf16(Hfd + (size_t)g * 512 + col, ud);   // buffers zeroed
            int ps = pslot[g];
            if (ps >= 0) atom_pk_bf16(Hdt + (size_t)ps * 512 + col, ud);
          } else {
            atom_pk_bf16(Htd + (size_t)g * 512 + col, ud);
          }
        }
      }
      // producer commit: atomics ack'd at coherent point, then count rows
      asm volatile("s_waitcnt vmcnt(0)" ::: "memory");
      __syncthreads();
      if (tid == 0) {
        __hip_atomic_fetch_add(doneP + d, (unsigned int)rows,
                               __ATOMIC_RELAXED, __HIP_MEMORY_SCOPE_AGENT);
        __hip_atomic_fetch_add(ctr + 512 + pass, (unsigned int)rows,
                               __ATOMIC_RELAXED, __HIP_MEMORY_SCOPE_AGENT);
      }
    }
  }

  // tail finalize: wait both passes fully done, stream compact -> out (f32)
  level_wait(ctr + 512, (unsigned int)NG * 32u);
  level_wait(ctr + 513, (unsigned int)NG * 32u);
  #pragma unroll
  for (int it = 0; it < 4; ++it) {
    const int g = bi * 128 + it * 32 + (tid >> 4);
    const int part = tid & 15;
    const int e = sched[g];
    const int b = e >> 8, node = e & 255;
    float* dst = out + ((size_t)b * NL + node) * 1024;
    const bool isroot = (node == root_index[b]);
    float* dst2 = out + (size_t)NB * NL * 1024 + (size_t)b * 1024;
    const unsigned short* s1 = Hfd + (size_t)g * 512 + part * 32;
    const unsigned short* s2 = Htd + (size_t)g * 512 + part * 32;
    #pragma unroll
    for (int half = 0; half < 2; ++half) {
      const unsigned short* s = half ? s2 : s1;
      const int o = half * 512 + part * 32;
      #pragma unroll
      for (int j = 0; j < 4; ++j) {
        short8 v = *(const short8*)(s + j * 8);
        f32x4 lo, hi;
        #pragma unroll
        for (int q = 0; q < 4; ++q) {
          lo[q] = bf2f((unsigned short)v[q]);
          hi[q] = bf2f((unsigned short)v[4 + q]);
        }
        __builtin_nontemporal_store(lo, (f32x4*)(dst + o + j * 8));
        __builtin_nontemporal_store(hi, (f32x4*)(dst + o + j * 8 + 4));
        if (isroot) {
          *(f32x4*)(dst2 + o + j * 8) = lo;
          *(f32x4*)(dst2 + o + j * 8 + 4) = hi;
        }
      }
    }
  }
}

extern "C" void kernel_launch(void* const* d_in, const int* in_sizes, int n_in,
                              void* d_out, int out_size, void* d_ws, size_t ws_size,
                              hipStream_t stream) {
  (void)in_sizes; (void)n_in; (void)out_size; (void)ws_size;
  const float* emb      = (const float*)d_in[0];
  const int*   td_pidx  = (const int*)d_in[4];
  const float* td_pval  = (const float*)d_in[5];
  const int*   root_idx = (const int*)d_in[6];
  const float* dt_Wx    = (const float*)d_in[7];
  const float* dt_Uh    = (const float*)d_in[8];
  const float* dt_b     = (const float*)d_in[9];
  const float* td_Wx    = (const float*)d_in[10];
  const float* td_Uh    = (const float*)d_in[11];
  const float* td_b     = (const float*)d_in[12];
  float* out = (float*)d_out;

  unsigned short* wt   = (unsigned short*)d_ws;
  unsigned short* Xc   = wt + (size_t)4 * 1536 * 512;
  unsigned short* Hdt  = Xc + (size_t)NG * NH;      // ---- zeroed region start
  unsigned short* Htd  = Hdt + (size_t)NG * NH;
  unsigned short* Hfd  = Htd + (size_t)NG * NH;
  unsigned short* zrow = Hfd + (size_t)NG * NH;
  unsigned int*   ctr  = (unsigned int*)(zrow + NH); // 520 u32 ---- zeroed end
  int* sched = (int*)(ctr + 520);
  int* meta  = sched + NG;
  int* gidx  = meta + 520;
  int* pslot = gidx + NG;

  const size_t zbytes = (size_t)3 * NG * NH * 2 + NH * 2 + 520 * 4;
  (void)hipMemsetAsync(Hdt, 0, zbytes, stream);     // Hdt,Htd,Hfd,zrow,ctr
  prep_wt4<<<dim3(48, 16, 4), dim3(256), 0, stream>>>(dt_Wx, dt_Uh, td_Wx, td_Uh, wt);
  prep_sched<<<dim3(1), dim3(256), 0, stream>>>(td_pidx, td_pval, sched, meta, gidx, pslot);
  prep_xc<<<dim3(NG / 4), dim3(256), 0, stream>>>(emb, sched, Xc);

  (void)hipFuncSetAttribute((const void*)tree_gru,
                            hipFuncAttributeMaxDynamicSharedMemorySize, 163840);

  void* args[] = {
    (void*)&dt_b, (void*)&td_b, (void*)&wt, (void*)&Xc, (void*)&Hdt, (void*)&Htd,
    (void*)&Hfd, (void*)&zrow, (void*)&meta, (void*)&pslot, (void*)&ctr,
    (void*)&sched, (void*)&root_idx, (void*)&out
  };
  (void)hipLaunchCooperativeKernel((const void*)tree_gru, dim3(256), dim3(512),
                                   args, 163840u, stream);
}

// Round 11
// 1507.423 us; speedup vs baseline: 1.1142x; 1.1142x over previous
//
#include <hip/hip_runtime.h>

// Tree-GRU encoder, round 11 = round 10 minus the per-level L2 nuke.
//  - R10's acquire fence (agent scope) in level_wait lowered to a full XCD-L2
//    invalidate at EVERY level for EVERY block -> all tile staging re-read
//    from LLC under 256-block contention (~10k cy/chunk vs 930 compute).
//  - Staleness audit: state rows are written ONLY by device-coherent atomics
//    (LLC), strictly before any reader's level. The only stale-L2-line source
//    was hipMemsetAsync's blit. Fix: zero-fill kernel with sc0 sc1 nt stores
//    (write-through, no L2 allocation) -> acquire fence can be dropped, and
//    plain staging loads may now legally cache in L2 (32 same-XCD colgroup
//    blocks share each A-tile line).
//
// ws (~141 MB): wt 4x[1536][512] | Xc[NG][512] | Hdt|Htd|Hfd [NG][512] |
//               zrow[512] | ctr u32[520] | sched/meta/gidx/pslot

#define NL 256
#define NB 128
#define NH 512
#define NG (NB * NL)

typedef short short8 __attribute__((ext_vector_type(8)));
typedef float f32x4 __attribute__((ext_vector_type(4)));

__device__ __forceinline__ float bf2f(unsigned short u) {
  union { unsigned int i; float f; } c; c.i = ((unsigned int)u) << 16; return c.f;
}
__device__ __forceinline__ unsigned short f2bf(float f) {
  union { float f; unsigned int i; } c; c.f = f;
  return (unsigned short)((c.i + 0x7FFFu + ((c.i >> 16) & 1u)) >> 16);  // RNE
}
__device__ __forceinline__ short8 pk_bf16(f32x4 a, f32x4 b) {
  union { unsigned int u[4]; short8 s; } r;
  asm("v_cvt_pk_bf16_f32 %0, %1, %2" : "=v"(r.u[0]) : "v"(a[0]), "v"(a[1]));
  asm("v_cvt_pk_bf16_f32 %0, %1, %2" : "=v"(r.u[1]) : "v"(a[2]), "v"(a[3]));
  asm("v_cvt_pk_bf16_f32 %0, %1, %2" : "=v"(r.u[2]) : "v"(b[0]), "v"(b[1]));
  asm("v_cvt_pk_bf16_f32 %0, %1, %2" : "=v"(r.u[3]) : "v"(b[2]), "v"(b[3]));
  return r.s;
}
__device__ __forceinline__ void atom_pk_bf16(unsigned short* p, unsigned int ud) {
  asm volatile("global_atomic_pk_add_bf16 %0, %1, off" :: "v"((void*)p), "v"(ud) : "memory");
}

// NO acquire fence: state reads are plain loads; safety relies on (a) writers
// being device-coherent atomics that complete (vmcnt 0) before the counter
// add, (b) no local L2 ever holding a pre-write copy (nt zero-fill).
__device__ __forceinline__ void level_wait(unsigned int* c, unsigned int target) {
  if (threadIdx.x == 0) {
    while (__hip_atomic_load(c, __ATOMIC_RELAXED, __HIP_MEMORY_SCOPE_AGENT) < target)
      __builtin_amdgcn_s_sleep(2);
  }
  __syncthreads();
}

// ---- prep: zero state buffers with write-through no-allocate stores ----
__global__ void prep_zero(f32x4* __restrict__ base, int n16) {
  const f32x4 z = {0.f, 0.f, 0.f, 0.f};
  int i = blockIdx.x * blockDim.x + threadIdx.x;
  int stride = gridDim.x * blockDim.x;
  for (int j = i; j < n16; j += stride) {
    asm volatile("global_store_dwordx4 %0, %1, off sc0 sc1 nt"
                 :: "v"((void*)(base + j)), "v"(z) : "memory");
  }
}

// ---- prep: 4 weight matrices [512][1536] f32 -> transposed [1536][512] bf16 ----
__global__ void prep_wt4(const float* __restrict__ w0, const float* __restrict__ w1,
                         const float* __restrict__ w2, const float* __restrict__ w3,
                         unsigned short* __restrict__ wt) {
  __shared__ float t[32][33];
  const float* w = blockIdx.z == 0 ? w0 : blockIdx.z == 1 ? w1 : blockIdx.z == 2 ? w2 : w3;
  unsigned short* dst = wt + (size_t)blockIdx.z * 1536 * 512;
  int n0 = blockIdx.x * 32, k0 = blockIdx.y * 32;
  int tx = threadIdx.x & 31, ty = threadIdx.x >> 5;
  #pragma unroll
  for (int i = 0; i < 4; ++i)
    t[ty + 8 * i][tx] = w[(size_t)(k0 + ty + 8 * i) * 1536 + n0 + tx];
  __syncthreads();
  #pragma unroll
  for (int i = 0; i < 4; ++i)
    dst[(size_t)(n0 + ty + 8 * i) * 512 + k0 + tx] = f2bf(t[tx][ty + 8 * i]);
}

// ---- prep: depths, level buckets, slots, parent slots (1 block, 256 thr) ----
__global__ void prep_sched(const int* __restrict__ td_pidx,
                           const float* __restrict__ td_pval,
                           int* __restrict__ sched, int* __restrict__ meta,
                           int* __restrict__ gidx, int* __restrict__ pslot) {
  __shared__ unsigned char dep[NB][NL];
  __shared__ unsigned short cnb[NB][256];
  __shared__ int cnt[256];
  __shared__ int off[257];
  __shared__ int dmax_s;
  const int tid = threadIdx.x;
  for (int j = tid; j < NB * 256; j += 256) ((unsigned short*)cnb)[j] = 0;
  if (tid == 0) dmax_s = 0;
  __syncthreads();
  if (tid < NB) {
    int b = tid, lmax = 0;
    for (int i = 0; i < NL; ++i) {
      float pv = td_pval[i * NB + b];
      int pi = td_pidx[i * NB + b];
      int d = (pv != 0.f) ? (int)dep[b][pi] + 1 : 0;   // head[i] < i
      dep[b][i] = (unsigned char)d;
      cnb[b][d]++;
      lmax = max(lmax, d);
    }
    atomicMax(&dmax_s, lmax);
  }
  __syncthreads();
  {
    int s = 0;
    for (int b = 0; b < NB; ++b) s += cnb[b][tid];
    cnt[tid] = s;
  }
  __syncthreads();
  if (tid == 0) {
    int s = 0;
    for (int d = 0; d < 256; ++d) { off[d] = s; s += cnt[d]; }
    off[256] = s;
  }
  __syncthreads();
  {
    int run = off[tid];
    for (int b = 0; b < NB; ++b) {
      int t = cnb[b][tid];
      cnb[b][tid] = (unsigned short)run;
      run += t;
    }
  }
  __syncthreads();
  if (tid < NB) {
    int b = tid;
    for (int i = 0; i < NL; ++i) {
      float pv = td_pval[i * NB + b];
      int pi = td_pidx[i * NB + b];
      int d = dep[b][i];
      int g = cnb[b][d]++;
      sched[g] = (b << 8) | i;
      gidx[b * NL + i] = g;
      pslot[g] = (pv != 0.f) ? gidx[b * NL + pi] : -1;
    }
  }
  if (tid == 0) meta[0] = dmax_s;
  __syncthreads();
  meta[1 + tid] = off[tid];
  meta[257 + tid] = cnt[tid];
}

// ---- prep: gather emb rows into slot order, f32 -> bf16 ----
__global__ void prep_xc(const float* __restrict__ emb, const int* __restrict__ sched,
                        unsigned short* __restrict__ Xc) {
  int g = blockIdx.x * 4 + (threadIdx.x >> 6);
  int lane = threadIdx.x & 63;
  int e = sched[g];
  int b = e >> 8, node = e & 255;
  const float* src = emb + ((size_t)node * NB + b) * 512 + lane * 8;
  f32x4 v0 = *(const f32x4*)src;
  f32x4 v1 = *(const f32x4*)(src + 4);
  *(short8*)(Xc + (size_t)g * 512 + lane * 8) = pk_bf16(v0, v1);
}

// ---- main fused kernel, flag-synced ----
// grid = 256 x 512 thr (8 waves, 1/CU). bi = cg*8 + pass*4 + rep.
// Block tile: 256 rows x 16 cols. Wave w owns rows [w*32, +32) (2 A-frags).
// LDS: B weights 98304 | Xb 32768 | Hb 32768 = 163840.
__launch_bounds__(512, 2)
__global__ void tree_gru(const float* __restrict__ dt_b,
                         const float* __restrict__ td_b,
                         const unsigned short* __restrict__ wt,
                         const unsigned short* __restrict__ Xc,
                         unsigned short* __restrict__ Hdt,
                         unsigned short* __restrict__ Htd,
                         unsigned short* __restrict__ Hfd,
                         const unsigned short* __restrict__ zrow,
                         const int* __restrict__ meta,
                         const int* __restrict__ pslot,
                         unsigned int* __restrict__ ctr,
                         const int* __restrict__ sched,
                         const int* __restrict__ root_index,
                         float* __restrict__ out) {
  extern __shared__ unsigned char lds[];
  const int tid = threadIdx.x;
  const int bi  = blockIdx.x;
  const int cg   = bi >> 3;          // 0..31 col group (16 cols)
  const int pass = (bi >> 2) & 1;    // 0 = DT bottom-up, 1 = TD top-down
  const int rep  = bi & 3;           // row-tile replica
  const int w  = tid >> 6, l = tid & 63;
  const int lm = l & 15, kg = l >> 4;
  const int col = cg * 16 + lm;

  // stage weight slices: [mat(Wx,Uh)][gate(r,z,n)][n16][k512] bf16, XOR-swizzled
  for (int idx = tid; idx < 6144; idx += 512) {
    int k8  = idx & 63;
    int n   = (idx >> 6) & 15;
    int g   = (idx >> 10) % 3;
    int mat = idx / 3072;
    const unsigned short* src = wt + (size_t)(pass * 2 + mat) * (1536 * 512)
                                   + (size_t)(g * 512 + cg * 16 + n) * 512 + k8 * 8;
    short8 v = *(const short8*)src;
    int off = ((mat * 3 + g) * 16 + n) * 1024 + ((k8 * 16) ^ ((n & 7) << 4));
    *(short8*)(lds + off) = v;
  }
  unsigned char* Xb = lds + 98304;
  unsigned char* Hb = lds + 98304 + 32768;
  __syncthreads();

  const float* bias = pass ? td_b : dt_b;
  const float br = bias[col], bz = bias[NH + col], bn = bias[2 * NH + col];
  const int base_wr = (0 * 16 + lm) * 1024;
  const int base_wz = (1 * 16 + lm) * 1024;
  const int base_wn = (2 * 16 + lm) * 1024;
  const int base_ur = (3 * 16 + lm) * 1024;
  const int base_uz = (4 * 16 + lm) * 1024;
  const int base_un = (5 * 16 + lm) * 1024;
  const int wswz = (lm & 7) << 4;
  const int srow = tid >> 1;                     // A-stage: 256 rows x 2 halves
  const int shalf = (tid & 1) * 4;               // 4 slot offset (64B)
  const int ck = cg >> 2;                        // chunk holding this block's cols
  const int ccw = 2 * ((cg & 3) * 16 + lm);      // byte off of col within chunk row
  const int ccslot = ccw >> 4, ccin = ccw & 15;
  const int Dmax = meta[0];
  unsigned int* doneP = ctr + pass * 256;

  for (int p = 0; p <= Dmax; ++p) {
    const int d = pass ? p : (Dmax - p);
    const int off_d = meta[1 + d];
    const int cnt_d = meta[257 + d];
    const int T = (cnt_d + 255) >> 8;
    if (T <= rep) continue;                      // no tiles -> no wait
    const int dl = pass ? d - 1 : d + 1;         // dependency level
    if (dl >= 0 && dl <= Dmax)
      level_wait(doneP + dl, (unsigned int)meta[257 + dl] * 32u);
    for (int t = rep; t < T; t += 4) {
      const int g0 = off_d + t * 256;
      const int rows = min(256, cnt_d - t * 256);
      // staging sources: row srow (clamped), 64B half each — coalesced
      const int gg = g0 + min(srow, rows - 1);
      const unsigned short* sx = Xc + (size_t)gg * 512 + (tid & 1) * 32;
      const unsigned short* sh;
      if (pass == 0) {
        sh = Hdt + (size_t)gg * 512 + (tid & 1) * 32;
      } else {
        int ps = pslot[gg];
        sh = (ps >= 0 ? Htd + (size_t)ps * 512 : zrow) + (tid & 1) * 32;
      }
      const int c0 = (ck + 1) & 7;               // rotated order ends at ck
      short8 rx[4], rh[4];
      #pragma unroll
      for (int j = 0; j < 4; ++j) {
        rx[j] = *(const short8*)(sx + c0 * 64 + j * 8);
        rh[j] = *(const short8*)(sh + c0 * 64 + j * 8);
      }
      f32x4 aR[2], aZ[2], aXN[2], aHN[2];
      #pragma unroll
      for (int f = 0; f < 2; ++f) {
        aR[f] = (f32x4){0,0,0,0}; aZ[f] = (f32x4){0,0,0,0};
        aXN[f] = (f32x4){0,0,0,0}; aHN[f] = (f32x4){0,0,0,0};
      }
      #pragma unroll
      for (int ci = 0; ci < 8; ++ci) {
        const int c = (ck + 1 + ci) & 7;
        __syncthreads();                         // prev chunk consumed
        #pragma unroll
        for (int j = 0; j < 4; ++j) {
          const int so = ((shalf + j) ^ (srow & 7)) << 4;
          *(short8*)(Xb + srow * 128 + so) = rx[j];
          *(short8*)(Hb + srow * 128 + so) = rh[j];
        }
        if (ci < 7) {
          const int cn = (ck + 2 + ci) & 7;
          #pragma unroll
          for (int j = 0; j < 4; ++j) {
            rx[j] = *(const short8*)(sx + cn * 64 + j * 8);
            rh[j] = *(const short8*)(sh + cn * 64 + j * 8);
          }
        }
        __syncthreads();                         // chunk visible
        #pragma unroll
        for (int ks = 0; ks < 2; ++ks) {
          const int so = (((ks << 2) | kg) ^ (lm & 7)) << 4;
          const int r0 = (w * 32 + lm) * 128;
          const int r1 = (w * 32 + 16 + lm) * 128;
          short8 ax0 = *(const short8*)(Xb + r0 + so);
          short8 ax1 = *(const short8*)(Xb + r1 + so);
          short8 ah0 = *(const short8*)(Hb + r0 + so);
          short8 ah1 = *(const short8*)(Hb + r1 + so);
          const int kb = (c * 128 + ks * 64 + kg * 16) ^ wswz;
          short8 bwr = *(const short8*)(lds + base_wr + kb);
          short8 bwz = *(const short8*)(lds + base_wz + kb);
          short8 bwn = *(const short8*)(lds + base_wn + kb);
          short8 bur = *(const short8*)(lds + base_ur + kb);
          short8 buz = *(const short8*)(lds + base_uz + kb);
          short8 bun = *(const short8*)(lds + base_un + kb);
          aR[0]  = __builtin_amdgcn_mfma_f32_16x16x32_bf16(ax0, bwr, aR[0], 0, 0, 0);
          aR[1]  = __builtin_amdgcn_mfma_f32_16x16x32_bf16(ax1, bwr, aR[1], 0, 0, 0);
          aZ[0]  = __builtin_amdgcn_mfma_f32_16x16x32_bf16(ax0, bwz, aZ[0], 0, 0, 0);
          aZ[1]  = __builtin_amdgcn_mfma_f32_16x16x32_bf16(ax1, bwz, aZ[1], 0, 0, 0);
          aXN[0] = __builtin_amdgcn_mfma_f32_16x16x32_bf16(ax0, bwn, aXN[0], 0, 0, 0);
          aXN[1] = __builtin_amdgcn_mfma_f32_16x16x32_bf16(ax1, bwn, aXN[1], 0, 0, 0);
          aR[0]  = __builtin_amdgcn_mfma_f32_16x16x32_bf16(ah0, bur, aR[0], 0, 0, 0);
          aR[1]  = __builtin_amdgcn_mfma_f32_16x16x32_bf16(ah1, bur, aR[1], 0, 0, 0);
          aZ[0]  = __builtin_amdgcn_mfma_f32_16x16x32_bf16(ah0, buz, aZ[0], 0, 0, 0);
          aZ[1]  = __builtin_amdgcn_mfma_f32_16x16x32_bf16(ah1, buz, aZ[1], 0, 0, 0);
          aHN[0] = __builtin_amdgcn_mfma_f32_16x16x32_bf16(ah0, bun, aHN[0], 0, 0, 0);
          aHN[1] = __builtin_amdgcn_mfma_f32_16x16x32_bf16(ah1, bun, aHN[1], 0, 0, 0);
        }
      }
      // epilogue: Hb holds chunk ck -> hprev from LDS. Row = w*32+f*16+kg*4+q.
      #pragma unroll
      for (int fq = 0; fq < 8; ++fq) {
        const int f = fq >> 2, q = fq & 3;
        const int r = w * 32 + f * 16 + kg * 4 + q;
        if (r >= rows) continue;
        const int g = g0 + r;
        const float hprev = bf2f(*(const unsigned short*)(
            Hb + r * 128 + (((ccslot ^ (r & 7)) << 4) | ccin)));
        float rr = 1.f / (1.f + __expf(-(aR[f][q] + br)));
        float zz = 1.f / (1.f + __expf(-(aZ[f][q] + bz)));
        float e2 = __expf(2.f * (aXN[f][q] + bn + rr * aHN[f][q]));
        float nn = (e2 - 1.f) / (e2 + 1.f);      // tanh
        float h = (1.f - zz) * nn + zz * hprev;
        float ho = __shfl_xor(h, 1);
        if (!(lm & 1)) {
          unsigned int ud;
          asm("v_cvt_pk_bf16_f32 %0, %1, %2" : "=v"(ud) : "v"(h), "v"(ho));
          if (pass == 0) {
            atom_pk_bf16(Hfd + (size_t)g * 512 + col, ud);   // buffers zeroed
            int ps = pslot[g];
            if (ps >= 0) atom_pk_bf16(Hdt + (size_t)ps * 512 + col, ud);
          } else {
            atom_pk_bf16(Htd + (size_t)g * 512 + col, ud);
          }
        }
      }
      // producer commit: atomics ack'd at coherent point, then count rows
      asm volatile("s_waitcnt vmcnt(0)" ::: "memory");
      __syncthreads();
      if (tid == 0) {
        __hip_atomic_fetch_add(doneP + d, (unsigned int)rows,
                               __ATOMIC_RELAXED, __HIP_MEMORY_SCOPE_AGENT);
        __hip_atomic_fetch_add(ctr + 512 + pass, (unsigned int)rows,
                               __ATOMIC_RELAXED, __HIP_MEMORY_SCOPE_AGENT);
      }
    }
  }

  // tail finalize: wait both passes fully done, stream compact -> out (f32)
  level_wait(ctr + 512, (unsigned int)NG * 32u);
  level_wait(ctr + 513, (unsigned int)NG * 32u);
  #pragma unroll
  for (int it = 0; it < 4; ++it) {
    const int g = bi * 128 + it * 32 + (tid >> 4);
    const int part = tid & 15;
    const int e = sched[g];
    const int b = e >> 8, node = e & 255;
    float* dst = out + ((size_t)b * NL + node) * 1024;
    const bool isroot = (node == root_index[b]);
    float* dst2 = out + (size_t)NB * NL * 1024 + (size_t)b * 1024;
    const unsigned short* s1 = Hfd + (size_t)g * 512 + part * 32;
    const unsigned short* s2 = Htd + (size_t)g * 512 + part * 32;
    #pragma unroll
    for (int half = 0; half < 2; ++half) {
      const unsigned short* s = half ? s2 : s1;
      const int o = half * 512 + part * 32;
      #pragma unroll
      for (int j = 0; j < 4; ++j) {
        short8 v = *(const short8*)(s + j * 8);
        f32x4 lo, hi;
        #pragma unroll
        for (int q = 0; q < 4; ++q) {
          lo[q] = bf2f((unsigned short)v[q]);
          hi[q] = bf2f((unsigned short)v[4 + q]);
        }
        __builtin_nontemporal_store(lo, (f32x4*)(dst + o + j * 8));
        __builtin_nontemporal_store(hi, (f32x4*)(dst + o + j * 8 + 4));
        if (isroot) {
          *(f32x4*)(dst2 + o + j * 8) = lo;
          *(f32x4*)(dst2 + o + j * 8 + 4) = hi;
        }
      }
    }
  }
}

extern "C" void kernel_launch(void* const* d_in, const int* in_sizes, int n_in,
                              void* d_out, int out_size, void* d_ws, size_t ws_size,
                              hipStream_t stream) {
  (void)in_sizes; (void)n_in; (void)out_size; (void)ws_size;
  const float* emb      = (const float*)d_in[0];
  const int*   td_pidx  = (const int*)d_in[4];
  const float* td_pval  = (const float*)d_in[5];
  const int*   root_idx = (const int*)d_in[6];
  const float* dt_Wx    = (const float*)d_in[7];
  const float* dt_Uh    = (const float*)d_in[8];
  const float* dt_b     = (const float*)d_in[9];
  const float* td_Wx    = (const float*)d_in[10];
  const float* td_Uh    = (const float*)d_in[11];
  const float* td_b     = (const float*)d_in[12];
  float* out = (float*)d_out;

  unsigned short* wt   = (unsigned short*)d_ws;
  unsigned short* Xc   = wt + (size_t)4 * 1536 * 512;
  unsigned short* Hdt  = Xc + (size_t)NG * NH;      // ---- zeroed region start
  unsigned short* Htd  = Hdt + (size_t)NG * NH;
  unsigned short* Hfd  = Htd + (size_t)NG * NH;
  unsigned short* zrow = Hfd + (size_t)NG * NH;
  unsigned int*   ctr  = (unsigned int*)(zrow + NH); // 520 u32 ---- zeroed end
  int* sched = (int*)(ctr + 520);
  int* meta  = sched + NG;
  int* gidx  = meta + 520;
  int* pslot = gidx + NG;

  // zero Hdt..ctr with write-through no-L2-allocate stores (16B units)
  const int n16 = (int)(((size_t)3 * NG * NH * 2 + NH * 2 + 520 * 4) / 16);
  prep_zero<<<dim3(2048), dim3(256), 0, stream>>>((f32x4*)Hdt, n16);
  prep_wt4<<<dim3(48, 16, 4), dim3(256), 0, stream>>>(dt_Wx, dt_Uh, td_Wx, td_Uh, wt);
  prep_sched<<<dim3(1), dim3(256), 0, stream>>>(td_pidx, td_pval, sched, meta, gidx, pslot);
  prep_xc<<<dim3(NG / 4), dim3(256), 0, stream>>>(emb, sched, Xc);

  (void)hipFuncSetAttribute((const void*)tree_gru,
                            hipFuncAttributeMaxDynamicSharedMemorySize, 163840);

  void* args[] = {
    (void*)&dt_b, (void*)&td_b, (void*)&wt, (void*)&Xc, (void*)&Hdt, (void*)&Htd,
    (void*)&Hfd, (void*)&zrow, (void*)&meta, (void*)&pslot, (void*)&ctr,
    (void*)&sched, (void*)&root_idx, (void*)&out
  };
  (void)hipLaunchCooperativeKernel((const void*)tree_gru, dim3(256), dim3(512),
                                   args, 163840u, stream);
}

// Round 12
// 1477.813 us; speedup vs baseline: 1.1365x; 1.0200x over previous
//
#include <hip/hip_runtime.h>

// Tree-GRU encoder, round 12 = round 11 with atomics minimized.
//  - THEORY: 25M global_atomic_pk_add_bf16 RMWs/call at the LLC coherent point
//    are the wall (~uncoalesceable 4B RMWs). Hfd and Htd have a single writer
//    per (g,col) and no reader before the level flag -> plain write-through
//    stores (sc0 sc1: device-visible, wave-coalesced into 128B bursts).
//    Only Hdt (sibling scatter to shared parent) keeps atomic add.
//  - Everything else byte-identical to R11 (per-level dataflow flags, no
//    acquire fence, nt zero-fill so no stale L2 lines, rotated chunks,
//    LDS hprev, XCD-aligned rep mapping).
//
// ws (~141 MB): wt 4x[1536][512] | Xc[NG][512] | Hdt|Htd|Hfd [NG][512] |
//               zrow[512] | ctr u32[520] | sched/meta/gidx/pslot

#define NL 256
#define NB 128
#define NH 512
#define NG (NB * NL)

typedef short short8 __attribute__((ext_vector_type(8)));
typedef float f32x4 __attribute__((ext_vector_type(4)));

__device__ __forceinline__ float bf2f(unsigned short u) {
  union { unsigned int i; float f; } c; c.i = ((unsigned int)u) << 16; return c.f;
}
__device__ __forceinline__ unsigned short f2bf(float f) {
  union { float f; unsigned int i; } c; c.f = f;
  return (unsigned short)((c.i + 0x7FFFu + ((c.i >> 16) & 1u)) >> 16);  // RNE
}
__device__ __forceinline__ short8 pk_bf16(f32x4 a, f32x4 b) {
  union { unsigned int u[4]; short8 s; } r;
  asm("v_cvt_pk_bf16_f32 %0, %1, %2" : "=v"(r.u[0]) : "v"(a[0]), "v"(a[1]));
  asm("v_cvt_pk_bf16_f32 %0, %1, %2" : "=v"(r.u[1]) : "v"(a[2]), "v"(a[3]));
  asm("v_cvt_pk_bf16_f32 %0, %1, %2" : "=v"(r.u[2]) : "v"(b[0]), "v"(b[1]));
  asm("v_cvt_pk_bf16_f32 %0, %1, %2" : "=v"(r.u[3]) : "v"(b[2]), "v"(b[3]));
  return r.s;
}
__device__ __forceinline__ void atom_pk_bf16(unsigned short* p, unsigned int ud) {
  asm volatile("global_atomic_pk_add_bf16 %0, %1, off" :: "v"((void*)p), "v"(ud) : "memory");
}
// device-visible coalesced store (write-through to coherent point, no RMW)
__device__ __forceinline__ void store_u32_wt(unsigned short* p, unsigned int v) {
  asm volatile("global_store_dword %0, %1, off sc0 sc1" :: "v"((void*)p), "v"(v) : "memory");
}

// NO acquire fence: writers are device-visible (atomic or sc0sc1 stores) and
// drained (vmcnt 0) before the counter add; no local L2 ever holds a stale
// pre-write copy (nt zero-fill; rows read only at their own level).
__device__ __forceinline__ void level_wait(unsigned int* c, unsigned int target) {
  if (threadIdx.x == 0) {
    while (__hip_atomic_load(c, __ATOMIC_RELAXED, __HIP_MEMORY_SCOPE_AGENT) < target)
      __builtin_amdgcn_s_sleep(2);
  }
  __syncthreads();
}

// ---- prep: zero state buffers with write-through no-allocate stores ----
__global__ void prep_zero(f32x4* __restrict__ base, int n16) {
  const f32x4 z = {0.f, 0.f, 0.f, 0.f};
  int i = blockIdx.x * blockDim.x + threadIdx.x;
  int stride = gridDim.x * blockDim.x;
  for (int j = i; j < n16; j += stride) {
    asm volatile("global_store_dwordx4 %0, %1, off sc0 sc1 nt"
                 :: "v"((void*)(base + j)), "v"(z) : "memory");
  }
}

// ---- prep: 4 weight matrices [512][1536] f32 -> transposed [1536][512] bf16 ----
__global__ void prep_wt4(const float* __restrict__ w0, const float* __restrict__ w1,
                         const float* __restrict__ w2, const float* __restrict__ w3,
                         unsigned short* __restrict__ wt) {
  __shared__ float t[32][33];
  const float* w = blockIdx.z == 0 ? w0 : blockIdx.z == 1 ? w1 : blockIdx.z == 2 ? w2 : w3;
  unsigned short* dst = wt + (size_t)blockIdx.z * 1536 * 512;
  int n0 = blockIdx.x * 32, k0 = blockIdx.y * 32;
  int tx = threadIdx.x & 31, ty = threadIdx.x >> 5;
  #pragma unroll
  for (int i = 0; i < 4; ++i)
    t[ty + 8 * i][tx] = w[(size_t)(k0 + ty + 8 * i) * 1536 + n0 + tx];
  __syncthreads();
  #pragma unroll
  for (int i = 0; i < 4; ++i)
    dst[(size_t)(n0 + ty + 8 * i) * 512 + k0 + tx] = f2bf(t[tx][ty + 8 * i]);
}

// ---- prep: depths, level buckets, slots, parent slots (1 block, 256 thr) ----
__global__ void prep_sched(const int* __restrict__ td_pidx,
                           const float* __restrict__ td_pval,
                           int* __restrict__ sched, int* __restrict__ meta,
                           int* __restrict__ gidx, int* __restrict__ pslot) {
  __shared__ unsigned char dep[NB][NL];
  __shared__ unsigned short cnb[NB][256];
  __shared__ int cnt[256];
  __shared__ int off[257];
  __shared__ int dmax_s;
  const int tid = threadIdx.x;
  for (int j = tid; j < NB * 256; j += 256) ((unsigned short*)cnb)[j] = 0;
  if (tid == 0) dmax_s = 0;
  __syncthreads();
  if (tid < NB) {
    int b = tid, lmax = 0;
    for (int i = 0; i < NL; ++i) {
      float pv = td_pval[i * NB + b];
      int pi = td_pidx[i * NB + b];
      int d = (pv != 0.f) ? (int)dep[b][pi] + 1 : 0;   // head[i] < i
      dep[b][i] = (unsigned char)d;
      cnb[b][d]++;
      lmax = max(lmax, d);
    }
    atomicMax(&dmax_s, lmax);
  }
  __syncthreads();
  {
    int s = 0;
    for (int b = 0; b < NB; ++b) s += cnb[b][tid];
    cnt[tid] = s;
  }
  __syncthreads();
  if (tid == 0) {
    int s = 0;
    for (int d = 0; d < 256; ++d) { off[d] = s; s += cnt[d]; }
    off[256] = s;
  }
  __syncthreads();
  {
    int run = off[tid];
    for (int b = 0; b < NB; ++b) {
      int t = cnb[b][tid];
      cnb[b][tid] = (unsigned short)run;
      run += t;
    }
  }
  __syncthreads();
  if (tid < NB) {
    int b = tid;
    for (int i = 0; i < NL; ++i) {
      float pv = td_pval[i * NB + b];
      int pi = td_pidx[i * NB + b];
      int d = dep[b][i];
      int g = cnb[b][d]++;
      sched[g] = (b << 8) | i;
      gidx[b * NL + i] = g;
      pslot[g] = (pv != 0.f) ? gidx[b * NL + pi] : -1;
    }
  }
  if (tid == 0) meta[0] = dmax_s;
  __syncthreads();
  meta[1 + tid] = off[tid];
  meta[257 + tid] = cnt[tid];
}

// ---- prep: gather emb rows into slot order, f32 -> bf16 ----
__global__ void prep_xc(const float* __restrict__ emb, const int* __restrict__ sched,
                        unsigned short* __restrict__ Xc) {
  int g = blockIdx.x * 4 + (threadIdx.x >> 6);
  int lane = threadIdx.x & 63;
  int e = sched[g];
  int b = e >> 8, node = e & 255;
  const float* src = emb + ((size_t)node * NB + b) * 512 + lane * 8;
  f32x4 v0 = *(const f32x4*)src;
  f32x4 v1 = *(const f32x4*)(src + 4);
  *(short8*)(Xc + (size_t)g * 512 + lane * 8) = pk_bf16(v0, v1);
}

// ---- main fused kernel, flag-synced ----
// grid = 256 x 512 thr (8 waves, 1/CU). bi = cg*8 + pass*4 + rep.
// Block tile: 256 rows x 16 cols. Wave w owns rows [w*32, +32) (2 A-frags).
// LDS: B weights 98304 | Xb 32768 | Hb 32768 = 163840.
__launch_bounds__(512, 2)
__global__ void tree_gru(const float* __restrict__ dt_b,
                         const float* __restrict__ td_b,
                         const unsigned short* __restrict__ wt,
                         const unsigned short* __restrict__ Xc,
                         unsigned short* __restrict__ Hdt,
                         unsigned short* __restrict__ Htd,
                         unsigned short* __restrict__ Hfd,
                         const unsigned short* __restrict__ zrow,
                         const int* __restrict__ meta,
                         const int* __restrict__ pslot,
                         unsigned int* __restrict__ ctr,
                         const int* __restrict__ sched,
                         const int* __restrict__ root_index,
                         float* __restrict__ out) {
  extern __shared__ unsigned char lds[];
  const int tid = threadIdx.x;
  const int bi  = blockIdx.x;
  const int cg   = bi >> 3;          // 0..31 col group (16 cols)
  const int pass = (bi >> 2) & 1;    // 0 = DT bottom-up, 1 = TD top-down
  const int rep  = bi & 3;           // row-tile replica
  const int w  = tid >> 6, l = tid & 63;
  const int lm = l & 15, kg = l >> 4;
  const int col = cg * 16 + lm;

  // stage weight slices: [mat(Wx,Uh)][gate(r,z,n)][n16][k512] bf16, XOR-swizzled
  for (int idx = tid; idx < 6144; idx += 512) {
    int k8  = idx & 63;
    int n   = (idx >> 6) & 15;
    int g   = (idx >> 10) % 3;
    int mat = idx / 3072;
    const unsigned short* src = wt + (size_t)(pass * 2 + mat) * (1536 * 512)
                                   + (size_t)(g * 512 + cg * 16 + n) * 512 + k8 * 8;
    short8 v = *(const short8*)src;
    int off = ((mat * 3 + g) * 16 + n) * 1024 + ((k8 * 16) ^ ((n & 7) << 4));
    *(short8*)(lds + off) = v;
  }
  unsigned char* Xb = lds + 98304;
  unsigned char* Hb = lds + 98304 + 32768;
  __syncthreads();

  const float* bias = pass ? td_b : dt_b;
  const float br = bias[col], bz = bias[NH + col], bn = bias[2 * NH + col];
  const int base_wr = (0 * 16 + lm) * 1024;
  const int base_wz = (1 * 16 + lm) * 1024;
  const int base_wn = (2 * 16 + lm) * 1024;
  const int base_ur = (3 * 16 + lm) * 1024;
  const int base_uz = (4 * 16 + lm) * 1024;
  const int base_un = (5 * 16 + lm) * 1024;
  const int wswz = (lm & 7) << 4;
  const int srow = tid >> 1;                     // A-stage: 256 rows x 2 halves
  const int shalf = (tid & 1) * 4;               // 4 slot offset (64B)
  const int ck = cg >> 2;                        // chunk holding this block's cols
  const int ccw = 2 * ((cg & 3) * 16 + lm);      // byte off of col within chunk row
  const int ccslot = ccw >> 4, ccin = ccw & 15;
  const int Dmax = meta[0];
  unsigned int* doneP = ctr + pass * 256;

  for (int p = 0; p <= Dmax; ++p) {
    const int d = pass ? p : (Dmax - p);
    const int off_d = meta[1 + d];
    const int cnt_d = meta[257 + d];
    const int T = (cnt_d + 255) >> 8;
    if (T <= rep) continue;                      // no tiles -> no wait
    const int dl = pass ? d - 1 : d + 1;         // dependency level
    if (dl >= 0 && dl <= Dmax)
      level_wait(doneP + dl, (unsigned int)meta[257 + dl] * 32u);
    for (int t = rep; t < T; t += 4) {
      const int g0 = off_d + t * 256;
      const int rows = min(256, cnt_d - t * 256);
      // staging sources: row srow (clamped), 64B half each — coalesced
      const int gg = g0 + min(srow, rows - 1);
      const unsigned short* sx = Xc + (size_t)gg * 512 + (tid & 1) * 32;
      const unsigned short* sh;
      if (pass == 0) {
        sh = Hdt + (size_t)gg * 512 + (tid & 1) * 32;
      } else {
        int ps = pslot[gg];
        sh = (ps >= 0 ? Htd + (size_t)ps * 512 : zrow) + (tid & 1) * 32;
      }
      const int c0 = (ck + 1) & 7;               // rotated order ends at ck
      short8 rx[4], rh[4];
      #pragma unroll
      for (int j = 0; j < 4; ++j) {
        rx[j] = *(const short8*)(sx + c0 * 64 + j * 8);
        rh[j] = *(const short8*)(sh + c0 * 64 + j * 8);
      }
      f32x4 aR[2], aZ[2], aXN[2], aHN[2];
      #pragma unroll
      for (int f = 0; f < 2; ++f) {
        aR[f] = (f32x4){0,0,0,0}; aZ[f] = (f32x4){0,0,0,0};
        aXN[f] = (f32x4){0,0,0,0}; aHN[f] = (f32x4){0,0,0,0};
      }
      #pragma unroll
      for (int ci = 0; ci < 8; ++ci) {
        const int c = (ck + 1 + ci) & 7;
        __syncthreads();                         // prev chunk consumed
        #pragma unroll
        for (int j = 0; j < 4; ++j) {
          const int so = ((shalf + j) ^ (srow & 7)) << 4;
          *(short8*)(Xb + srow * 128 + so) = rx[j];
          *(short8*)(Hb + srow * 128 + so) = rh[j];
        }
        if (ci < 7) {
          const int cn = (ck + 2 + ci) & 7;
          #pragma unroll
          for (int j = 0; j < 4; ++j) {
            rx[j] = *(const short8*)(sx + cn * 64 + j * 8);
            rh[j] = *(const short8*)(sh + cn * 64 + j * 8);
          }
        }
        __syncthreads();                         // chunk visible
        #pragma unroll
        for (int ks = 0; ks < 2; ++ks) {
          const int so = (((ks << 2) | kg) ^ (lm & 7)) << 4;
          const int r0 = (w * 32 + lm) * 128;
          const int r1 = (w * 32 + 16 + lm) * 128;
          short8 ax0 = *(const short8*)(Xb + r0 + so);
          short8 ax1 = *(const short8*)(Xb + r1 + so);
          short8 ah0 = *(const short8*)(Hb + r0 + so);
          short8 ah1 = *(const short8*)(Hb + r1 + so);
          const int kb = (c * 128 + ks * 64 + kg * 16) ^ wswz;
          short8 bwr = *(const short8*)(lds + base_wr + kb);
          short8 bwz = *(const short8*)(lds + base_wz + kb);
          short8 bwn = *(const short8*)(lds + base_wn + kb);
          short8 bur = *(const short8*)(lds + base_ur + kb);
          short8 buz = *(const short8*)(lds + base_uz + kb);
          short8 bun = *(const short8*)(lds + base_un + kb);
          aR[0]  = __builtin_amdgcn_mfma_f32_16x16x32_bf16(ax0, bwr, aR[0], 0, 0, 0);
          aR[1]  = __builtin_amdgcn_mfma_f32_16x16x32_bf16(ax1, bwr, aR[1], 0, 0, 0);
          aZ[0]  = __builtin_amdgcn_mfma_f32_16x16x32_bf16(ax0, bwz, aZ[0], 0, 0, 0);
          aZ[1]  = __builtin_amdgcn_mfma_f32_16x16x32_bf16(ax1, bwz, aZ[1], 0, 0, 0);
          aXN[0] = __builtin_amdgcn_mfma_f32_16x16x32_bf16(ax0, bwn, aXN[0], 0, 0, 0);
          aXN[1] = __builtin_amdgcn_mfma_f32_16x16x32_bf16(ax1, bwn, aXN[1], 0, 0, 0);
          aR[0]  = __builtin_amdgcn_mfma_f32_16x16x32_bf16(ah0, bur, aR[0], 0, 0, 0);
          aR[1]  = __builtin_amdgcn_mfma_f32_16x16x32_bf16(ah1, bur, aR[1], 0, 0, 0);
          aZ[0]  = __builtin_amdgcn_mfma_f32_16x16x32_bf16(ah0, buz, aZ[0], 0, 0, 0);
          aZ[1]  = __builtin_amdgcn_mfma_f32_16x16x32_bf16(ah1, buz, aZ[1], 0, 0, 0);
          aHN[0] = __builtin_amdgcn_mfma_f32_16x16x32_bf16(ah0, bun, aHN[0], 0, 0, 0);
          aHN[1] = __builtin_amdgcn_mfma_f32_16x16x32_bf16(ah1, bun, aHN[1], 0, 0, 0);
        }
      }
      // epilogue: Hb holds chunk ck -> hprev from LDS. Row = w*32+f*16+kg*4+q.
      #pragma unroll
      for (int fq = 0; fq < 8; ++fq) {
        const int f = fq >> 2, q = fq & 3;
        const int r = w * 32 + f * 16 + kg * 4 + q;
        if (r >= rows) continue;
        const int g = g0 + r;
        const float hprev = bf2f(*(const unsigned short*)(
            Hb + r * 128 + (((ccslot ^ (r & 7)) << 4) | ccin)));
        float rr = 1.f / (1.f + __expf(-(aR[f][q] + br)));
        float zz = 1.f / (1.f + __expf(-(aZ[f][q] + bz)));
        float e2 = __expf(2.f * (aXN[f][q] + bn + rr * aHN[f][q]));
        float nn = (e2 - 1.f) / (e2 + 1.f);      // tanh
        float h = (1.f - zz) * nn + zz * hprev;
        float ho = __shfl_xor(h, 1);
        if (!(lm & 1)) {
          unsigned int ud;
          asm("v_cvt_pk_bf16_f32 %0, %1, %2" : "=v"(ud) : "v"(h), "v"(ho));
          if (pass == 0) {
            store_u32_wt(Hfd + (size_t)g * 512 + col, ud);       // single writer
            int ps = pslot[g];
            if (ps >= 0) atom_pk_bf16(Hdt + (size_t)ps * 512 + col, ud);  // scatter-sum
          } else {
            store_u32_wt(Htd + (size_t)g * 512 + col, ud);       // single writer
          }
        }
      }
      // producer commit: stores/atomics drained to coherent point, then count
      asm volatile("s_waitcnt vmcnt(0)" ::: "memory");
      __syncthreads();
      if (tid == 0) {
        __hip_atomic_fetch_add(doneP + d, (unsigned int)rows,
                               __ATOMIC_RELAXED, __HIP_MEMORY_SCOPE_AGENT);
        __hip_atomic_fetch_add(ctr + 512 + pass, (unsigned int)rows,
                               __ATOMIC_RELAXED, __HIP_MEMORY_SCOPE_AGENT);
      }
    }
  }

  // tail finalize: wait both passes fully done, stream compact -> out (f32)
  level_wait(ctr + 512, (unsigned int)NG * 32u);
  level_wait(ctr + 513, (unsigned int)NG * 32u);
  #pragma unroll
  for (int it = 0; it < 4; ++it) {
    const int g = bi * 128 + it * 32 + (tid >> 4);
    const int part = tid & 15;
    const int e = sched[g];
    const int b = e >> 8, node = e & 255;
    float* dst = out + ((size_t)b * NL + node) * 1024;
    const bool isroot = (node == root_index[b]);
    float* dst2 = out + (size_t)NB * NL * 1024 + (size_t)b * 1024;
    const unsigned short* s1 = Hfd + (size_t)g * 512 + part * 32;
    const unsigned short* s2 = Htd + (size_t)g * 512 + part * 32;
    #pragma unroll
    for (int half = 0; half < 2; ++half) {
      const unsigned short* s = half ? s2 : s1;
      const int o = half * 512 + part * 32;
      #pragma unroll
      for (int j = 0; j < 4; ++j) {
        short8 v = *(const short8*)(s + j * 8);
        f32x4 lo, hi;
        #pragma unroll
        for (int q = 0; q < 4; ++q) {
          lo[q] = bf2f((unsigned short)v[q]);
          hi[q] = bf2f((unsigned short)v[4 + q]);
        }
        __builtin_nontemporal_store(lo, (f32x4*)(dst + o + j * 8));
        __builtin_nontemporal_store(hi, (f32x4*)(dst + o + j * 8 + 4));
        if (isroot) {
          *(f32x4*)(dst2 + o + j * 8) = lo;
          *(f32x4*)(dst2 + o + j * 8 + 4) = hi;
        }
      }
    }
  }
}

extern "C" void kernel_launch(void* const* d_in, const int* in_sizes, int n_in,
                              void* d_out, int out_size, void* d_ws, size_t ws_size,
                              hipStream_t stream) {
  (void)in_sizes; (void)n_in; (void)out_size; (void)ws_size;
  const float* emb      = (const float*)d_in[0];
  const int*   td_pidx  = (const int*)d_in[4];
  const float* td_pval  = (const float*)d_in[5];
  const int*   root_idx = (const int*)d_in[6];
  const float* dt_Wx    = (const float*)d_in[7];
  const float* dt_Uh    = (const float*)d_in[8];
  const float* dt_b     = (const float*)d_in[9];
  const float* td_Wx    = (const float*)d_in[10];
  const float* td_Uh    = (const float*)d_in[11];
  const float* td_b     = (const float*)d_in[12];
  float* out = (float*)d_out;

  unsigned short* wt   = (unsigned short*)d_ws;
  unsigned short* Xc   = wt + (size_t)4 * 1536 * 512;
  unsigned short* Hdt  = Xc + (size_t)NG * NH;      // ---- zeroed region start
  unsigned short* Htd  = Hdt + (size_t)NG * NH;
  unsigned short* Hfd  = Htd + (size_t)NG * NH;
  unsigned short* zrow = Hfd + (size_t)NG * NH;
  unsigned int*   ctr  = (unsigned int*)(zrow + NH); // 520 u32 ---- zeroed end
  int* sched = (int*)(ctr + 520);
  int* meta  = sched + NG;
  int* gidx  = meta + 520;
  int* pslot = gidx + NG;

  // zero Hdt..ctr with write-through no-L2-allocate stores (16B units)
  const int n16 = (int)(((size_t)3 * NG * NH * 2 + NH * 2 + 520 * 4) / 16);
  prep_zero<<<dim3(2048), dim3(256), 0, stream>>>((f32x4*)Hdt, n16);
  prep_wt4<<<dim3(48, 16, 4), dim3(256), 0, stream>>>(dt_Wx, dt_Uh, td_Wx, td_Uh, wt);
  prep_sched<<<dim3(1), dim3(256), 0, stream>>>(td_pidx, td_pval, sched, meta, gidx, pslot);
  prep_xc<<<dim3(NG / 4), dim3(256), 0, stream>>>(emb, sched, Xc);

  (void)hipFuncSetAttribute((const void*)tree_gru,
                            hipFuncAttributeMaxDynamicSharedMemorySize, 163840);

  void* args[] = {
    (void*)&dt_b, (void*)&td_b, (void*)&wt, (void*)&Xc, (void*)&Hdt, (void*)&Htd,
    (void*)&Hfd, (void*)&zrow, (void*)&meta, (void*)&pslot, (void*)&ctr,
    (void*)&sched, (void*)&root_idx, (void*)&out
  };
  (void)hipLaunchCooperativeKernel((const void*)tree_gru, dim3(256), dim3(512),
                                   args, 163840u, stream);
}

// Round 13
// 1397.789 us; speedup vs baseline: 1.2016x; 1.0573x over previous
//
#include <hip/hip_runtime.h>

// Tree-GRU encoder, round 13 = round 12 + latency-overlap levers:
//  - double-buffered A-staging LDS (128-row tiles; 96K weights + 4x16K bufs
//    = 160KB), 3-chunk-deep register load pipeline, ONE barrier per chunk.
//  - per-LEVEL vmcnt(0)+counter (not per tile): tile stores drain off the
//    critical path.
//  - T14 reorder: next tile's staging loads are issued BEFORE this tile's
//    epilogue stores -> loads are older in vmcnt order, never wait on the
//    store/atomic drain.
// Everything else identical to R12 (flags, no fence, nt zero-fill, rotated
// chunks ending at own column chunk -> hprev from LDS, wt stores for
// single-writer buffers, atomic only for children-sum).

#define NL 256
#define NB 128
#define NH 512
#define NG (NB * NL)

typedef short short8 __attribute__((ext_vector_type(8)));
typedef float f32x4 __attribute__((ext_vector_type(4)));

__device__ __forceinline__ float bf2f(unsigned short u) {
  union { unsigned int i; float f; } c; c.i = ((unsigned int)u) << 16; return c.f;
}
__device__ __forceinline__ unsigned short f2bf(float f) {
  union { float f; unsigned int i; } c; c.f = f;
  return (unsigned short)((c.i + 0x7FFFu + ((c.i >> 16) & 1u)) >> 16);  // RNE
}
__device__ __forceinline__ short8 pk_bf16(f32x4 a, f32x4 b) {
  union { unsigned int u[4]; short8 s; } r;
  asm("v_cvt_pk_bf16_f32 %0, %1, %2" : "=v"(r.u[0]) : "v"(a[0]), "v"(a[1]));
  asm("v_cvt_pk_bf16_f32 %0, %1, %2" : "=v"(r.u[1]) : "v"(a[2]), "v"(a[3]));
  asm("v_cvt_pk_bf16_f32 %0, %1, %2" : "=v"(r.u[2]) : "v"(b[0]), "v"(b[1]));
  asm("v_cvt_pk_bf16_f32 %0, %1, %2" : "=v"(r.u[3]) : "v"(b[2]), "v"(b[3]));
  return r.s;
}
__device__ __forceinline__ void atom_pk_bf16(unsigned short* p, unsigned int ud) {
  asm volatile("global_atomic_pk_add_bf16 %0, %1, off" :: "v"((void*)p), "v"(ud) : "memory");
}
__device__ __forceinline__ void store_u32_wt(unsigned short* p, unsigned int v) {
  asm volatile("global_store_dword %0, %1, off sc0 sc1" :: "v"((void*)p), "v"(v) : "memory");
}

__device__ __forceinline__ void level_wait(unsigned int* c, unsigned int target) {
  if (threadIdx.x == 0) {
    while (__hip_atomic_load(c, __ATOMIC_RELAXED, __HIP_MEMORY_SCOPE_AGENT) < target)
      __builtin_amdgcn_s_sleep(2);
  }
  __syncthreads();
}

// ---- prep: zero state buffers with write-through no-allocate stores ----
__global__ void prep_zero(f32x4* __restrict__ base, int n16) {
  const f32x4 z = {0.f, 0.f, 0.f, 0.f};
  int i = blockIdx.x * blockDim.x + threadIdx.x;
  int stride = gridDim.x * blockDim.x;
  for (int j = i; j < n16; j += stride) {
    asm volatile("global_store_dwordx4 %0, %1, off sc0 sc1 nt"
                 :: "v"((void*)(base + j)), "v"(z) : "memory");
  }
}

// ---- prep: 4 weight matrices [512][1536] f32 -> transposed [1536][512] bf16 ----
__global__ void prep_wt4(const float* __restrict__ w0, const float* __restrict__ w1,
                         const float* __restrict__ w2, const float* __restrict__ w3,
                         unsigned short* __restrict__ wt) {
  __shared__ float t[32][33];
  const float* w = blockIdx.z == 0 ? w0 : blockIdx.z == 1 ? w1 : blockIdx.z == 2 ? w2 : w3;
  unsigned short* dst = wt + (size_t)blockIdx.z * 1536 * 512;
  int n0 = blockIdx.x * 32, k0 = blockIdx.y * 32;
  int tx = threadIdx.x & 31, ty = threadIdx.x >> 5;
  #pragma unroll
  for (int i = 0; i < 4; ++i)
    t[ty + 8 * i][tx] = w[(size_t)(k0 + ty + 8 * i) * 1536 + n0 + tx];
  __syncthreads();
  #pragma unroll
  for (int i = 0; i < 4; ++i)
    dst[(size_t)(n0 + ty + 8 * i) * 512 + k0 + tx] = f2bf(t[tx][ty + 8 * i]);
}

// ---- prep: depths, level buckets, slots, parent slots (1 block, 256 thr) ----
__global__ void prep_sched(const int* __restrict__ td_pidx,
                           const float* __restrict__ td_pval,
                           int* __restrict__ sched, int* __restrict__ meta,
                           int* __restrict__ gidx, int* __restrict__ pslot) {
  __shared__ unsigned char dep[NB][NL];
  __shared__ unsigned short cnb[NB][256];
  __shared__ int cnt[256];
  __shared__ int off[257];
  __shared__ int dmax_s;
  const int tid = threadIdx.x;
  for (int j = tid; j < NB * 256; j += 256) ((unsigned short*)cnb)[j] = 0;
  if (tid == 0) dmax_s = 0;
  __syncthreads();
  if (tid < NB) {
    int b = tid, lmax = 0;
    for (int i = 0; i < NL; ++i) {
      float pv = td_pval[i * NB + b];
      int pi = td_pidx[i * NB + b];
      int d = (pv != 0.f) ? (int)dep[b][pi] + 1 : 0;   // head[i] < i
      dep[b][i] = (unsigned char)d;
      cnb[b][d]++;
      lmax = max(lmax, d);
    }
    atomicMax(&dmax_s, lmax);
  }
  __syncthreads();
  {
    int s = 0;
    for (int b = 0; b < NB; ++b) s += cnb[b][tid];
    cnt[tid] = s;
  }
  __syncthreads();
  if (tid == 0) {
    int s = 0;
    for (int d = 0; d < 256; ++d) { off[d] = s; s += cnt[d]; }
    off[256] = s;
  }
  __syncthreads();
  {
    int run = off[tid];
    for (int b = 0; b < NB; ++b) {
      int t = cnb[b][tid];
      cnb[b][tid] = (unsigned short)run;
      run += t;
    }
  }
  __syncthreads();
  if (tid < NB) {
    int b = tid;
    for (int i = 0; i < NL; ++i) {
      float pv = td_pval[i * NB + b];
      int pi = td_pidx[i * NB + b];
      int d = dep[b][i];
      int g = cnb[b][d]++;
      sched[g] = (b << 8) | i;
      gidx[b * NL + i] = g;
      pslot[g] = (pv != 0.f) ? gidx[b * NL + pi] : -1;
    }
  }
  if (tid == 0) meta[0] = dmax_s;
  __syncthreads();
  meta[1 + tid] = off[tid];
  meta[257 + tid] = cnt[tid];
}

// ---- prep: gather emb rows into slot order, f32 -> bf16 ----
__global__ void prep_xc(const float* __restrict__ emb, const int* __restrict__ sched,
                        unsigned short* __restrict__ Xc) {
  int g = blockIdx.x * 4 + (threadIdx.x >> 6);
  int lane = threadIdx.x & 63;
  int e = sched[g];
  int b = e >> 8, node = e & 255;
  const float* src = emb + ((size_t)node * NB + b) * 512 + lane * 8;
  f32x4 v0 = *(const f32x4*)src;
  f32x4 v1 = *(const f32x4*)(src + 4);
  *(short8*)(Xc + (size_t)g * 512 + lane * 8) = pk_bf16(v0, v1);
}

// staging reg<->LDS helpers (macros keep indices compile-time, rule #20)
#define LDJ(j, rx, rh)                                            \
  { const int c_ = (ck + 1 + (j)) & 7;                            \
    rx[0] = *(const short8*)(sx + c_ * 64);                       \
    rx[1] = *(const short8*)(sx + c_ * 64 + 8);                   \
    rh[0] = *(const short8*)(sh + c_ * 64);                       \
    rh[1] = *(const short8*)(sh + c_ * 64 + 8); }
#define WRB(Xp, Hp, rx, rh)                                       \
  { *(short8*)((Xp) + srow * 128 + sw0) = rx[0];                  \
    *(short8*)((Xp) + srow * 128 + sw1) = rx[1];                  \
    *(short8*)((Hp) + srow * 128 + sw0) = rh[0];                  \
    *(short8*)((Hp) + srow * 128 + sw1) = rh[1]; }

// ---- main fused kernel, flag-synced, double-buffered ----
// grid = 256 x 512 thr (8 waves, 1/CU). bi = cg*8 + pass*4 + rep.
// Block tile: 128 rows x 16 cols. Wave w owns rows [w*16,+16).
// LDS: weights 98304 | Xb0,Hb0,Xb1,Hb1 4x16384 = 163840.
__launch_bounds__(512, 2)
__global__ void tree_gru(const float* __restrict__ dt_b,
                         const float* __restrict__ td_b,
                         const unsigned short* __restrict__ wt,
                         const unsigned short* __restrict__ Xc,
                         unsigned short* __restrict__ Hdt,
                         unsigned short* __restrict__ Htd,
                         unsigned short* __restrict__ Hfd,
                         const unsigned short* __restrict__ zrow,
                         const int* __restrict__ meta,
                         const int* __restrict__ pslot,
                         unsigned int* __restrict__ ctr,
                         const int* __restrict__ sched,
                         const int* __restrict__ root_index,
                         float* __restrict__ out) {
  extern __shared__ unsigned char lds[];
  const int tid = threadIdx.x;
  const int bi  = blockIdx.x;
  const int cg   = bi >> 3;          // 0..31 col group (16 cols)
  const int pass = (bi >> 2) & 1;    // 0 = DT bottom-up, 1 = TD top-down
  const int rep  = bi & 3;           // row-tile replica
  const int w  = tid >> 6, l = tid & 63;
  const int lm = l & 15, kg = l >> 4;
  const int col = cg * 16 + lm;

  // stage weight slices: [mat(Wx,Uh)][gate(r,z,n)][n16][k512] bf16, XOR-swizzled
  for (int idx = tid; idx < 6144; idx += 512) {
    int k8  = idx & 63;
    int n   = (idx >> 6) & 15;
    int g   = (idx >> 10) % 3;
    int mat = idx / 3072;
    const unsigned short* src = wt + (size_t)(pass * 2 + mat) * (1536 * 512)
                                   + (size_t)(g * 512 + cg * 16 + n) * 512 + k8 * 8;
    short8 v = *(const short8*)src;
    int off = ((mat * 3 + g) * 16 + n) * 1024 + ((k8 * 16) ^ ((n & 7) << 4));
    *(short8*)(lds + off) = v;
  }
  unsigned char* Xb0 = lds + 98304;
  unsigned char* Hb0 = Xb0 + 16384;
  unsigned char* Xb1 = Hb0 + 16384;
  unsigned char* Hb1 = Xb1 + 16384;
  __syncthreads();

  const float* bias = pass ? td_b : dt_b;
  const float br = bias[col], bz = bias[NH + col], bn = bias[2 * NH + col];
  const int base_wr = (0 * 16 + lm) * 1024;
  const int base_wz = (1 * 16 + lm) * 1024;
  const int base_wn = (2 * 16 + lm) * 1024;
  const int base_ur = (3 * 16 + lm) * 1024;
  const int base_uz = (4 * 16 + lm) * 1024;
  const int base_un = (5 * 16 + lm) * 1024;
  const int wswz = (lm & 7) << 4;
  const int srow = tid >> 2, sq = tid & 3;       // A-stage: 128 rows x 4 x 32B
  const int sw0 = ((sq * 2)     ^ (srow & 7)) << 4;
  const int sw1 = ((sq * 2 + 1) ^ (srow & 7)) << 4;
  const int ck = cg >> 2;                        // chunk holding this block's cols
  const int ccw = 2 * ((cg & 3) * 16 + lm);      // byte off of col within chunk row
  const int ccslot = ccw >> 4, ccin = ccw & 15;
  const int Dmax = meta[0];
  unsigned int* doneP = ctr + pass * 256;

  for (int p = 0; p <= Dmax; ++p) {
    const int d = pass ? p : (Dmax - p);
    const int off_d = meta[1 + d];
    const int cnt_d = meta[257 + d];
    const int T = (cnt_d + 127) >> 7;
    if (T <= rep) continue;                      // no tiles -> no wait
    const int dl = pass ? d - 1 : d + 1;         // dependency level
    if (dl >= 0 && dl <= Dmax)
      level_wait(doneP + dl, (unsigned int)meta[257 + dl] * 32u);

    unsigned int myrows = 0;
    // preload first tile's chunks 0,1 (rotated indices)
    const unsigned short *sx, *sh;
    {
      const int gg = off_d + min(rep * 128 + srow, cnt_d - 1);
      sx = Xc + (size_t)gg * 512 + sq * 16;
      if (pass == 0) sh = Hdt + (size_t)gg * 512 + sq * 16;
      else { int ps = pslot[gg]; sh = (ps >= 0 ? Htd + (size_t)ps * 512 : zrow) + sq * 16; }
    }
    short8 x0[2], h0[2], x1[2], h1[2];
    LDJ(0, x0, h0);
    LDJ(1, x1, h1);

    for (int t = rep; t < T; t += 4) {
      const int g0 = off_d + t * 128;
      const int rows = min(128, cnt_d - t * 128);
      __syncthreads();                           // prior tile reads complete
      WRB(Xb0, Hb0, x0, h0);                     // chunk j=0 -> buf0
      LDJ(2, x0, h0);
      __syncthreads();                           // buf0 visible

      f32x4 aR = {0,0,0,0}, aZ = {0,0,0,0}, aXN = {0,0,0,0}, aHN = {0,0,0,0};
      #pragma unroll
      for (int ci = 0; ci < 8; ++ci) {
        const int c = (ck + 1 + ci) & 7;
        const unsigned char* Ax = (ci & 1) ? Xb1 : Xb0;
        const unsigned char* Ah = (ci & 1) ? Hb1 : Hb0;
        #pragma unroll
        for (int ks = 0; ks < 2; ++ks) {
          const int so = (((ks << 2) | kg) ^ (lm & 7)) << 4;
          const int ar = (w * 16 + lm) * 128;
          short8 ax = *(const short8*)(Ax + ar + so);
          short8 ah = *(const short8*)(Ah + ar + so);
          const int kb = (c * 128 + ks * 64 + kg * 16) ^ wswz;
          short8 bwr = *(const short8*)(lds + base_wr + kb);
          short8 bwz = *(const short8*)(lds + base_wz + kb);
          short8 bwn = *(const short8*)(lds + base_wn + kb);
          short8 bur = *(const short8*)(lds + base_ur + kb);
          short8 buz = *(const short8*)(lds + base_uz + kb);
          short8 bun = *(const short8*)(lds + base_un + kb);
          aR  = __builtin_amdgcn_mfma_f32_16x16x32_bf16(ax, bwr, aR, 0, 0, 0);
          aZ  = __builtin_amdgcn_mfma_f32_16x16x32_bf16(ax, bwz, aZ, 0, 0, 0);
          aXN = __builtin_amdgcn_mfma_f32_16x16x32_bf16(ax, bwn, aXN, 0, 0, 0);
          aR  = __builtin_amdgcn_mfma_f32_16x16x32_bf16(ah, bur, aR, 0, 0, 0);
          aZ  = __builtin_amdgcn_mfma_f32_16x16x32_bf16(ah, buz, aZ, 0, 0, 0);
          aHN = __builtin_amdgcn_mfma_f32_16x16x32_bf16(ah, bun, aHN, 0, 0, 0);
        }
        if (ci < 7) {
          unsigned char* Wx = (ci & 1) ? Xb0 : Xb1;  // chunk ci+1 -> buf[(ci+1)&1]
          unsigned char* Wh = (ci & 1) ? Hb0 : Hb1;
          if ((ci & 1) == 0) {
            WRB(Wx, Wh, x1, h1);
            if (ci < 5) LDJ(ci + 3, x1, h1);
          } else {
            WRB(Wx, Wh, x0, h0);
            if (ci < 5) LDJ(ci + 3, x0, h0);
          }
          __syncthreads();
        }
      }
      // epilogue VALUES (no stores yet): Hb1 holds chunk ck -> hprev from LDS
      float hv[4];
      #pragma unroll
      for (int q = 0; q < 4; ++q) {
        const int r = w * 16 + kg * 4 + q;       // always < 128: LDS read safe
        const float hprev = bf2f(*(const unsigned short*)(
            Hb1 + r * 128 + (((ccslot ^ (r & 7)) << 4) | ccin)));
        float rr = 1.f / (1.f + __expf(-(aR[q] + br)));
        float zz = 1.f / (1.f + __expf(-(aZ[q] + bz)));
        float e2 = __expf(2.f * (aXN[q] + bn + rr * aHN[q]));
        float nn = (e2 - 1.f) / (e2 + 1.f);      // tanh
        hv[q] = (1.f - zz) * nn + zz * hprev;
      }
      // T14: issue NEXT tile's staging loads BEFORE this tile's stores
      if (t + 4 < T) {
        const int gg = off_d + min((t + 4) * 128 + srow, cnt_d - 1);
        sx = Xc + (size_t)gg * 512 + sq * 16;
        if (pass == 0) sh = Hdt + (size_t)gg * 512 + sq * 16;
        else { int ps = pslot[gg]; sh = (ps >= 0 ? Htd + (size_t)ps * 512 : zrow) + sq * 16; }
        LDJ(0, x0, h0);
        LDJ(1, x1, h1);
      }
      // stores (lanes lm, lm^1 share row -> pair-uniform predicate, shfl safe)
      #pragma unroll
      for (int q = 0; q < 4; ++q) {
        const int r = w * 16 + kg * 4 + q;
        if (r >= rows) continue;
        const int g = g0 + r;
        float ho = __shfl_xor(hv[q], 1);
        if (!(lm & 1)) {
          unsigned int ud;
          asm("v_cvt_pk_bf16_f32 %0, %1, %2" : "=v"(ud) : "v"(hv[q]), "v"(ho));
          if (pass == 0) {
            store_u32_wt(Hfd + (size_t)g * 512 + col, ud);       // single writer
            int ps = pslot[g];
            if (ps >= 0) atom_pk_bf16(Hdt + (size_t)ps * 512 + col, ud);
          } else {
            store_u32_wt(Htd + (size_t)g * 512 + col, ud);       // single writer
          }
        }
      }
      myrows += (unsigned int)rows;
    }
    // level commit: drain this level's stores once, then count
    asm volatile("s_waitcnt vmcnt(0)" ::: "memory");
    __syncthreads();
    if (tid == 0) {
      __hip_atomic_fetch_add(doneP + d, myrows,
                             __ATOMIC_RELAXED, __HIP_MEMORY_SCOPE_AGENT);
      __hip_atomic_fetch_add(ctr + 512 + pass, myrows,
                             __ATOMIC_RELAXED, __HIP_MEMORY_SCOPE_AGENT);
    }
  }

  // tail finalize: wait both passes fully done, stream compact -> out (f32)
  level_wait(ctr + 512, (unsigned int)NG * 32u);
  level_wait(ctr + 513, (unsigned int)NG * 32u);
  #pragma unroll
  for (int it = 0; it < 4; ++it) {
    const int g = bi * 128 + it * 32 + (tid >> 4);
    const int part = tid & 15;
    const int e = sched[g];
    const int b = e >> 8, node = e & 255;
    float* dst = out + ((size_t)b * NL + node) * 1024;
    const bool isroot = (node == root_index[b]);
    float* dst2 = out + (size_t)NB * NL * 1024 + (size_t)b * 1024;
    const unsigned short* s1 = Hfd + (size_t)g * 512 + part * 32;
    const unsigned short* s2 = Htd + (size_t)g * 512 + part * 32;
    #pragma unroll
    for (int half = 0; half < 2; ++half) {
      const unsigned short* s = half ? s2 : s1;
      const int o = half * 512 + part * 32;
      #pragma unroll
      for (int j = 0; j < 4; ++j) {
        short8 v = *(const short8*)(s + j * 8);
        f32x4 lo, hi;
        #pragma unroll
        for (int q = 0; q < 4; ++q) {
          lo[q] = bf2f((unsigned short)v[q]);
          hi[q] = bf2f((unsigned short)v[4 + q]);
        }
        __builtin_nontemporal_store(lo, (f32x4*)(dst + o + j * 8));
        __builtin_nontemporal_store(hi, (f32x4*)(dst + o + j * 8 + 4));
        if (isroot) {
          *(f32x4*)(dst2 + o + j * 8) = lo;
          *(f32x4*)(dst2 + o + j * 8 + 4) = hi;
        }
      }
    }
  }
}

extern "C" void kernel_launch(void* const* d_in, const int* in_sizes, int n_in,
                              void* d_out, int out_size, void* d_ws, size_t ws_size,
                              hipStream_t stream) {
  (void)in_sizes; (void)n_in; (void)out_size; (void)ws_size;
  const float* emb      = (const float*)d_in[0];
  const int*   td_pidx  = (const int*)d_in[4];
  const float* td_pval  = (const float*)d_in[5];
  const int*   root_idx = (const int*)d_in[6];
  const float* dt_Wx    = (const float*)d_in[7];
  const float* dt_Uh    = (const float*)d_in[8];
  const float* dt_b     = (const float*)d_in[9];
  const float* td_Wx    = (const float*)d_in[10];
  const float* td_Uh    = (const float*)d_in[11];
  const float* td_b     = (const float*)d_in[12];
  float* out = (float*)d_out;

  unsigned short* wt   = (unsigned short*)d_ws;
  unsigned short* Xc   = wt + (size_t)4 * 1536 * 512;
  unsigned short* Hdt  = Xc + (size_t)NG * NH;      // ---- zeroed region start
  unsigned short* Htd  = Hdt + (size_t)NG * NH;
  unsigned short* Hfd  = Htd + (size_t)NG * NH;
  unsigned short* zrow = Hfd + (size_t)NG * NH;
  unsigned int*   ctr  = (unsigned int*)(zrow + NH); // 520 u32 ---- zeroed end
  int* sched = (int*)(ctr + 520);
  int* meta  = sched + NG;
  int* gidx  = meta + 520;
  int* pslot = gidx + NG;

  // zero Hdt..ctr with write-through no-L2-allocate stores (16B units)
  const int n16 = (int)(((size_t)3 * NG * NH * 2 + NH * 2 + 520 * 4) / 16);
  prep_zero<<<dim3(2048), dim3(256), 0, stream>>>((f32x4*)Hdt, n16);
  prep_wt4<<<dim3(48, 16, 4), dim3(256), 0, stream>>>(dt_Wx, dt_Uh, td_Wx, td_Uh, wt);
  prep_sched<<<dim3(1), dim3(256), 0, stream>>>(td_pidx, td_pval, sched, meta, gidx, pslot);
  prep_xc<<<dim3(NG / 4), dim3(256), 0, stream>>>(emb, sched, Xc);

  (void)hipFuncSetAttribute((const void*)tree_gru,
                            hipFuncAttributeMaxDynamicSharedMemorySize, 163840);

  void* args[] = {
    (void*)&dt_b, (void*)&td_b, (void*)&wt, (void*)&Xc, (void*)&Hdt, (void*)&Htd,
    (void*)&Hfd, (void*)&zrow, (void*)&meta, (void*)&pslot, (void*)&ctr,
    (void*)&sched, (void*)&root_idx, (void*)&out
  };
  (void)hipLaunchCooperativeKernel((const void*)tree_gru, dim3(256), dim3(512),
                                   args, 163840u, stream);
}